// Round 1
// baseline (388.386 us; speedup 1.0000x reference)
//
#include <hip/hip_runtime.h>

// RUM cell, algebraically reduced:
//   R @ h = h + (cos-1)(a u + b v) + sin (a v - b u),  a = u.h, b = v.h
//   hidden_new = assoc_mem @ (R @ h)   -- batched matvec, reads 256MB once
// Shapes fixed: B=256, IN=512, H=512, 3H=1536.
// Round 4: K1 -> 256 blocks (1/CU), 2x3 micro (1B/FLOP), BK=64 dbuf (1 barrier/chunk);
//          K2 -> single 5-value reduction (analytic ||w||^2, w.h), early A prefetch.

#define EPSF 1e-12f

typedef float vfloat4 __attribute__((ext_vector_type(4)));

// ---------------- K1: proj = [inp|hid] @ [W_ih|W_hh]^T + b_ih + b_hh ----
// BM=32, BN=48, BK=64, 256 thr, 2x3 micro, double-buffered LDS.
// grid (32,8) = 256 blocks = exactly 1 per CU. VALU-bound ~12cyc/k.
#define WSTR 49   // 48 + 1: store banks 4*(t&7)+3g+j all-distinct -> <=2-way

__global__ __launch_bounds__(256) void gemm_proj(
    const float* __restrict__ inp, const float* __restrict__ hid,
    const float* __restrict__ W_ih, const float* __restrict__ W_hh,
    const float* __restrict__ b_ih, const float* __restrict__ b_hh,
    float* __restrict__ proj)
{
    __shared__ float Xs[2][64 * 34];     // [k][m], broadcast-read along m
    __shared__ float Ws[2][64 * WSTR];   // [k][n]
    const int t  = threadIdx.x;
    const int tx = t & 15;               // cols 3*tx .. +2
    const int ty = t >> 4;               // rows 2*ty .. +1
    const int col0 = blockIdx.x * 48;
    const int row0 = blockIdx.y * 32;
    // X staging: 32 rows x 64 k -> thread owns row lr, k = lk and lk+32
    const int lr = t >> 3;               // 0..31
    const int lk = (t & 7) * 4;          // 0..28
    // W staging: 48 rows x 64 k -> thread owns rows wr..wr+2 at k = wk
    const int wr = (t >> 4) * 3;         // 0,3,..,45
    const int wk = (t & 15) * 4;         // 0..60

    float acc[2][3] = {};

    const float* Xg = inp;
    const float* Wg = W_ih;
    float4 xv0 = *(const float4*)(Xg + (size_t)(row0 + lr) * 512 + lk);
    float4 xv1 = *(const float4*)(Xg + (size_t)(row0 + lr) * 512 + lk + 32);
    float4 wv0 = *(const float4*)(Wg + (size_t)(col0 + wr + 0) * 512 + wk);
    float4 wv1 = *(const float4*)(Wg + (size_t)(col0 + wr + 1) * 512 + wk);
    float4 wv2 = *(const float4*)(Wg + (size_t)(col0 + wr + 2) * 512 + wk);

    for (int cc = 0; cc < 16; ++cc) {
        float* Xb = Xs[cc & 1];
        float* Wb = Ws[cc & 1];
        Xb[(lk + 0) * 34 + lr] = xv0.x;
        Xb[(lk + 1) * 34 + lr] = xv0.y;
        Xb[(lk + 2) * 34 + lr] = xv0.z;
        Xb[(lk + 3) * 34 + lr] = xv0.w;
        Xb[(lk + 32) * 34 + lr] = xv1.x;
        Xb[(lk + 33) * 34 + lr] = xv1.y;
        Xb[(lk + 34) * 34 + lr] = xv1.z;
        Xb[(lk + 35) * 34 + lr] = xv1.w;
        Wb[(wk + 0) * WSTR + wr + 0] = wv0.x;
        Wb[(wk + 1) * WSTR + wr + 0] = wv0.y;
        Wb[(wk + 2) * WSTR + wr + 0] = wv0.z;
        Wb[(wk + 3) * WSTR + wr + 0] = wv0.w;
        Wb[(wk + 0) * WSTR + wr + 1] = wv1.x;
        Wb[(wk + 1) * WSTR + wr + 1] = wv1.y;
        Wb[(wk + 2) * WSTR + wr + 1] = wv1.z;
        Wb[(wk + 3) * WSTR + wr + 1] = wv1.w;
        Wb[(wk + 0) * WSTR + wr + 2] = wv2.x;
        Wb[(wk + 1) * WSTR + wr + 2] = wv2.y;
        Wb[(wk + 2) * WSTR + wr + 2] = wv2.z;
        Wb[(wk + 3) * WSTR + wr + 2] = wv2.w;

        // register prefetch of next chunk (hides global latency under compute)
        if (cc < 15) {
            const int nc = cc + 1;
            Xg = (nc & 8) ? hid  : inp;
            Wg = (nc & 8) ? W_hh : W_ih;
            const int k0 = (nc & 7) * 64;
            xv0 = *(const float4*)(Xg + (size_t)(row0 + lr) * 512 + k0 + lk);
            xv1 = *(const float4*)(Xg + (size_t)(row0 + lr) * 512 + k0 + lk + 32);
            wv0 = *(const float4*)(Wg + (size_t)(col0 + wr + 0) * 512 + k0 + wk);
            wv1 = *(const float4*)(Wg + (size_t)(col0 + wr + 1) * 512 + k0 + wk);
            wv2 = *(const float4*)(Wg + (size_t)(col0 + wr + 2) * 512 + k0 + wk);
        }

        // single barrier per chunk: stores went to buf[cc&1]; any wave that
        // could overwrite buf[cc&1] again must first pass barrier(cc+1).
        __syncthreads();
#pragma unroll 16
        for (int kk = 0; kk < 64; ++kk) {
            const float2 x2 = *(const float2*)&Xb[kk * 34 + 2 * ty];  // broadcast
            const float w0 = Wb[kk * WSTR + 3 * tx + 0];
            const float w1 = Wb[kk * WSTR + 3 * tx + 1];
            const float w2 = Wb[kk * WSTR + 3 * tx + 2];
            acc[0][0] += x2.x * w0; acc[0][1] += x2.x * w1; acc[0][2] += x2.x * w2;
            acc[1][0] += x2.y * w0; acc[1][1] += x2.y * w1; acc[1][2] += x2.y * w2;
        }
    }

    const int cbase = col0 + 3 * tx;
    const float bias0 = b_ih[cbase + 0] + b_hh[cbase + 0];
    const float bias1 = b_ih[cbase + 1] + b_hh[cbase + 1];
    const float bias2 = b_ih[cbase + 2] + b_hh[cbase + 2];
#pragma unroll
    for (int i = 0; i < 2; ++i) {
        const int r = row0 + 2 * ty + i;
        float* p = proj + (size_t)r * 1536 + cbase;
        p[0] = acc[i][0] + bias0;
        p[1] = acc[i][1] + bias1;
        p[2] = acc[i][2] + bias2;
    }
}

// ---------------- K2: fused rotate + batched matvec + epilogue ----------
// One block (1024 thr = 16 waves) per batch row b. Streams A[b] (1 MB).

__device__ __forceinline__ float dot4(vfloat4 a, float4 b) {
    return a.x * b.x + a.y * b.y + a.z * b.z + a.w * b.w;
}

__global__ __launch_bounds__(1024) void rum_fused(
    const float* __restrict__ proj, const float* __restrict__ hid,
    const float* __restrict__ A, float* __restrict__ out)
{
    __shared__ float4 Rh4[128];      // R @ hidden, 512 floats
    __shared__ float  hn[512];       // assoc_mem @ Rh
    __shared__ float4 red[16];
    __shared__ float  red1[16];
    float* Rh = (float*)Rh4;

    const int b = blockIdx.x;
    const int t = threadIdx.x;       // 0..1023
    const int lane = t & 63;
    const int wv = t >> 6;           // 0..15
    const int g = lane >> 4;         // row-in-quad 0..3
    const int c = lane & 15;         // column lane
    const float* prow = proj + (size_t)b * 1536;
    const vfloat4* Ab = (const vfloat4*)(A + (size_t)b * 262144);

    // early A prefetch: q=0 row chunk is independent of proj -> loads are in
    // flight while the stage-1 reduction runs (hides HBM ramp).
    const vfloat4* Ar0 = Ab + (size_t)(32 * wv + g) * 128;
    vfloat4 pf[8];
#pragma unroll
    for (int k = 0; k < 8; ++k) pf[k] = __builtin_nontemporal_load(Ar0 + c + 16 * k);

    // ---- stage 1: ONE 5-value block reduction (analytic ||w||^2 and w.h)
    float xe = 0.f, rr = 0.f, hh = 0.f, ug = 0.f;
    if (t < 512) {
        xe = prow[1024 + t];
        rr = prow[512 + t];
        hh = hid[(size_t)b * 512 + t];
        ug = prow[t];                // preload gate for stage 3
    }
    float4 p = { xe * xe, rr * rr, xe * rr, xe * hh };
    float pe = rr * hh;
#pragma unroll
    for (int off = 32; off >= 1; off >>= 1) {
        p.x += __shfl_xor(p.x, off, 64);
        p.y += __shfl_xor(p.y, off, 64);
        p.z += __shfl_xor(p.z, off, 64);
        p.w += __shfl_xor(p.w, off, 64);
        pe  += __shfl_xor(pe,  off, 64);
    }
    if (lane == 0) { red[wv] = p; red1[wv] = pe; }
    __syncthreads();
    float xx = 0.f, r2 = 0.f, xr = 0.f, xh = 0.f, rh = 0.f;
#pragma unroll
    for (int i = 0; i < 16; ++i) {
        float4 q = red[i];
        xx += q.x; r2 += q.y; xr += q.z; xh += q.w; rh += red1[i];
    }
    const float nx = fmaxf(sqrtf(xx), EPSF);
    const float nr = fmaxf(sqrtf(r2), EPSF);
    const float costh = xr / (nx * nr);
    const float sinth = sqrtf(fmaxf(1.0f - costh * costh, 0.0f));
    const float inx2 = 1.0f / (nx * nx);
    const float dot_ur = xr / nx;          // u . r
    const float a = xh / nx;               // u . h
    const float uu = xx * inx2;            // u . u (~1, handles eps clamp)
    const float ww = fmaxf(r2 - xr * xr * inx2 * (2.0f - uu), 0.0f);  // ||w||^2
    const float wh = rh - xr * xh * inx2;  // w . h
    const float nw = fmaxf(sqrtf(ww), EPSF);
    const float bb = wh / nw;              // v . h
    const float inw = 1.0f / nw;
    const float cm1 = costh - 1.0f;
    if (t < 512) {
        const float u = xe / nx;
        const float w = rr - dot_ur * u;
        const float v = w * inw;
        Rh[t] = hh + cm1 * (a * u + bb * v) + sinth * (a * v - bb * u);
    }
    __syncthreads();

    // ---- stage 2: hn = A[b] @ Rh. Wave wv rows [32wv,32wv+32), 4 rows/pass,
    //      16 lanes per row (c), 4-step xor reduce within 16-lane groups.
    float4 xr4[8];
#pragma unroll
    for (int k = 0; k < 8; ++k) xr4[k] = Rh4[c + 16 * k];

    {   // q = 0 from prefetched registers
        const int i = 32 * wv + g;
        float a0 = dot4(pf[0], xr4[0]) + dot4(pf[4], xr4[4]);
        float a1 = dot4(pf[1], xr4[1]) + dot4(pf[5], xr4[5]);
        float a2 = dot4(pf[2], xr4[2]) + dot4(pf[6], xr4[6]);
        float a3 = dot4(pf[3], xr4[3]) + dot4(pf[7], xr4[7]);
        float accq = (a0 + a1) + (a2 + a3);
#pragma unroll
        for (int off = 8; off >= 1; off >>= 1)
            accq += __shfl_xor(accq, off, 16);
        if (c == 0) hn[i] = accq;
    }
#pragma unroll 2
    for (int q = 1; q < 8; ++q) {
        const int i = 32 * wv + 4 * q + g;
        const vfloat4* Ar = Ab + (size_t)i * 128;
        float a0 = 0.f, a1 = 0.f, a2 = 0.f, a3 = 0.f;
#pragma unroll
        for (int k = 0; k < 8; k += 4) {
            vfloat4 v0 = __builtin_nontemporal_load(Ar + c + 16 * (k + 0));
            vfloat4 v1 = __builtin_nontemporal_load(Ar + c + 16 * (k + 1));
            vfloat4 v2 = __builtin_nontemporal_load(Ar + c + 16 * (k + 2));
            vfloat4 v3 = __builtin_nontemporal_load(Ar + c + 16 * (k + 3));
            a0 += dot4(v0, xr4[k + 0]);
            a1 += dot4(v1, xr4[k + 1]);
            a2 += dot4(v2, xr4[k + 2]);
            a3 += dot4(v3, xr4[k + 3]);
        }
        float accq = (a0 + a1) + (a2 + a3);
#pragma unroll
        for (int off = 8; off >= 1; off >>= 1)
            accq += __shfl_xor(accq, off, 16);
        if (c == 0) hn[i] = accq;
    }
    __syncthreads();

    // ---- stage 3: gate + relu + l2norm (scalar reduction)
    float tv = 0.f;
    if (t < 512) {
        const float cx = fmaxf(hn[t] + xe, 0.0f);
        tv = ug * hh + (1.0f - ug) * cx;
    }
    float s = tv * tv;
#pragma unroll
    for (int off = 32; off >= 1; off >>= 1) s += __shfl_xor(s, off, 64);
    if (lane == 0) red1[wv] = s;
    __syncthreads();
    float tot = 0.f;
#pragma unroll
    for (int i = 0; i < 16; ++i) tot += red1[i];
    const float inv = 1.0f / fmaxf(sqrtf(tot), EPSF);   // ETA = 1
    if (t < 512)
        out[(size_t)b * 512 + t] = tv * inv;
}

extern "C" void kernel_launch(void* const* d_in, const int* in_sizes, int n_in,
                              void* d_out, int out_size, void* d_ws, size_t ws_size,
                              hipStream_t stream)
{
    const float* inp  = (const float*)d_in[0];   // [256,512]
    const float* hid  = (const float*)d_in[1];   // [256,512]
    const float* A    = (const float*)d_in[2];   // [256,512,512]
    const float* W_ih = (const float*)d_in[3];   // [1536,512]
    const float* b_ih = (const float*)d_in[4];   // [1536]
    const float* W_hh = (const float*)d_in[5];   // [1536,512]
    const float* b_hh = (const float*)d_in[6];   // [1536]
    float* out = (float*)d_out;                  // [256,512]

    float* proj = (float*)d_ws;                  // 1.5 MB workspace

    gemm_proj<<<dim3(32, 8), 256, 0, stream>>>(inp, hid, W_ih, W_hh, b_ih, b_hh, proj);
    rum_fused<<<dim3(256), 1024, 0, stream>>>(proj, hid, A, out);
}